// Round 10
// baseline (498.431 us; speedup 1.0000x reference)
//
#include <hip/hip_runtime.h>
#include <cstdint>

#define L_DIM 2048
#define B_DIM 16
#define D_DIM 1024
#define M_DIM (L_DIM*B_DIM)   // 32768
#define N_DIM (3*D_DIM)       // 3072
#define K_DIM D_DIM           // 1024
#define NCH   (B_DIM*D_DIM)   // 16384 channels
#define SEG   64
#define SEGLEN (L_DIM/SEG)    // 32
#define CG    (NCH/8)         // 2048 channel-groups of 8

#define BK 64                 // K per tile-step
#define NKT (K_DIM/BK)        // 16 K-tiles
#define BUF 65536             // bytes per LDS buffer: A 32KB (8 slabs x 4KB) + B 32KB

typedef __bf16 bf16x8 __attribute__((ext_vector_type(8)));
typedef float f32x16 __attribute__((ext_vector_type(16)));

__device__ inline float bf2f(ushort u){ return __uint_as_float(((unsigned)u)<<16); }
__device__ inline ushort f2bf(float f){
  unsigned u = __float_as_uint(f);
  u += 0x7fffu + ((u>>16)&1u);          // RTNE
  return (ushort)(u>>16);
}

// fp32 -> bf16 convert, 8 elements per thread
__global__ __launch_bounds__(256) void cvt8(const float* __restrict__ in,
                                            ushort* __restrict__ out, int n8){
  int t = blockIdx.x*256 + threadIdx.x;
  if (t >= n8) return;
  const float4* p = (const float4*)(in + (size_t)t*8);
  float4 a = p[0], b = p[1];
  ushort r[8] = {f2bf(a.x),f2bf(a.y),f2bf(a.z),f2bf(a.w),
                 f2bf(b.x),f2bf(b.y),f2bf(b.z),f2bf(b.w)};
  *(uint4*)(out + (size_t)t*8) = *(const uint4*)r;
}

#define GLOAD(gp, lp) __builtin_amdgcn_global_load_lds( \
    (const __attribute__((address_space(1))) void*)(gp), \
    (__attribute__((address_space(3))) void*)(lp), 16, 0, 0)

// 256x256 tile, BK=64, 16 waves (4x4) of 64x64; mfma 32x32x16.
// LDS is K-slab-major: slab s (16B of K) x 256 rows, addr = s*4096 + row*16
// -> frag reads are 512B-contiguous per 32 lanes: conflict-free, no swizzle.
__global__ __launch_bounds__(1024, 4) void gemm_sru(
    const ushort* __restrict__ gA,  // M x K bf16
    const ushort* __restrict__ gB,  // N x K bf16
    const float* __restrict__ bias, // N fp32
    ushort* __restrict__ xbuf, ushort* __restrict__ zbuf, ushort* __restrict__ hbuf)
{
  __shared__ ulong2 lds_[2*BUF/16];   // 128 KiB
  char* ldsb = (char*)lds_;

  const int tid  = threadIdx.x;
  const int lane = tid & 63, w = tid >> 6;
  const int wr = (w>>2)*64;            // wave row base (0..192)
  const int wc = (w&3)*64;             // wave col base (0..192)
  const int l31 = lane & 31, l5 = lane >> 5;

  // XCD L2-grouping swizzle: xcd x owns mb in [x*16, x*16+16), nb-major order
  // so the 12 blocks sharing an A-panel (512KB, L2-fits) run concurrently on x.
  const int bid = blockIdx.x;
  const int xcd = bid & 7, idx = bid >> 3;        // idx 0..191
  const int mb = xcd*16 + idx/12, nb = idx % 12;
  const int bm = mb*256, bn = nb*256;

  // per-lane frag read bases (slab-major): slab = ks*2 + l5, row = wr/wc + f*32 + l31
  const char* pA = ldsb + l5*4096 + (wr + l31)*16;
  const char* pB = ldsb + 32768 + l5*4096 + (wc + l31)*16;

  // staging: chunk c = round*1024 + tid covers slab c>>8, row c&255; dest = c*16 (linear)
  const ushort* gAp = gA + (size_t)(bm + (tid & 255))*K_DIM + ((tid>>8)&3)*8;
  const ushort* gBp = gB + (size_t)(bn + (tid & 255))*K_DIM + ((tid>>8)&3)*8;

  f32x16 acc[2][2];
  #pragma unroll
  for (int i=0;i<2;i++)
    #pragma unroll
    for (int j=0;j<2;j++)
      #pragma unroll
      for (int r=0;r<16;r++) acc[i][j][r] = 0.f;

#define STAGE(tt) do{ \
    char* d = ldsb + ((tt)&1)*BUF; \
    GLOAD(gAp + (size_t)(tt)*BK,      d + tid*16);              /* slabs 0-3 */ \
    GLOAD(gAp + (size_t)(tt)*BK + 32, d + 16384 + tid*16);      /* slabs 4-7 */ \
    GLOAD(gBp + (size_t)(tt)*BK,      d + 32768 + tid*16); \
    GLOAD(gBp + (size_t)(tt)*BK + 32, d + 49152 + tid*16); \
  }while(0)

  // prologue: stage tile 0, wait, publish
  STAGE(0);
  __syncthreads();

  for (int t = 0; t < NKT; ++t) {
    const int bo = (t&1)*BUF;
    if (t < NKT-1) STAGE(t+1);      // other buffer; forced by tile-end syncthreads

    #pragma unroll
    for (int ks=0; ks<4; ++ks) {
      bf16x8 a0 = *(const bf16x8*)(pA + bo + ks*8192);
      bf16x8 a1 = *(const bf16x8*)(pA + bo + ks*8192 + 512);
      bf16x8 b0 = *(const bf16x8*)(pB + bo + ks*8192);
      bf16x8 b1 = *(const bf16x8*)(pB + bo + ks*8192 + 512);
      __builtin_amdgcn_s_setprio(1);
      acc[0][0] = __builtin_amdgcn_mfma_f32_32x32x16_bf16(a0, b0, acc[0][0], 0,0,0);
      acc[0][1] = __builtin_amdgcn_mfma_f32_32x32x16_bf16(a0, b1, acc[0][1], 0,0,0);
      acc[1][0] = __builtin_amdgcn_mfma_f32_32x32x16_bf16(a1, b0, acc[1][0], 0,0,0);
      acc[1][1] = __builtin_amdgcn_mfma_f32_32x32x16_bf16(a1, b1, acc[1][1], 0,0,0);
      __builtin_amdgcn_s_setprio(0);
    }
    __syncthreads();                // drains vmcnt (stage t+1 forced) + publishes
  }

  // ---- epilogue: acc -> LDS (bf16, bias+sigmoid, slot^row swizzle) -> coalesced ----
  // 32x32 C/D layout: col = lane&31, row = (reg&3) + 8*(reg>>2) + 4*(lane>>5)
  const int region = bn >> 10;
  ushort* dst = region==0 ? xbuf : (region==1 ? zbuf : hbuf);
  ushort* lds16 = (ushort*)ldsb;
  float bvv[2];
  bvv[0] = bias[bn + wc + l31];
  bvv[1] = bias[bn + wc + 32 + l31];

  #pragma unroll
  for (int fa=0; fa<2; ++fa)
    #pragma unroll
    for (int fb=0; fb<2; ++fb)
      #pragma unroll
      for (int r=0; r<16; ++r){
        int row = wr + fa*32 + (r&3) + ((r>>2)<<3) + (l5<<2);
        int col = wc + fb*32 + l31;
        float v = acc[fa][fb][r] + bvv[fb];
        if (region) v = 1.f/(1.f + __expf(-v));
        int slot = col >> 3;
        lds16[row*256 + (((slot ^ (row&31))&31)<<3) + (col&7)] = f2bf(v);
      }
  __syncthreads();
  const int cb = bn & (D_DIM-1);
  #pragma unroll
  for (int i=0;i<8;i++){
    int off = i*16384 + tid*16;               // byte in 256x512B tile
    int row = off >> 9;
    int slot = (off >> 4) & 31;
    int dcol = (off & 511) >> 1;
    const char* src = ldsb + row*512 + (((slot ^ (row&31))&31)<<4);
    *(uint4*)(dst + (size_t)(bm+row)*D_DIM + cb + dcol) = *(const uint4*)src;
  }
#undef STAGE
}

// Pass 1: per (segment, 8-channel group) compose affine coefficients
__global__ __launch_bounds__(256) void scan_pass1(
    const ushort* __restrict__ z, const ushort* __restrict__ x,
    float* __restrict__ Aout, float* __restrict__ Bout)
{
  int t = blockIdx.x*256 + threadIdx.x;   // 0..131071
  int cg = t & (CG-1), g = t >> 11;       // CG = 2048 = 2^11
  int c0 = cg*8;
  size_t base = (size_t)g*SEGLEN*NCH + c0;
  float A[8], Bc[8];
  #pragma unroll
  for (int j=0;j<8;j++){ A[j]=1.f; Bc[j]=0.f; }
  #pragma unroll 4
  for (int i=0;i<SEGLEN;i++){
    uint4 zv = *(const uint4*)(z + base + (size_t)i*NCH);
    uint4 xv = *(const uint4*)(x + base + (size_t)i*NCH);
    const ushort* zp = (const ushort*)&zv;
    const ushort* xp = (const ushort*)&xv;
    #pragma unroll
    for (int j=0;j<8;j++){
      float zf = bf2f(zp[j]);
      float a  = 1.f - zf;
      float bb = zf * bf2f(xp[j]);
      Bc[j] = a*Bc[j] + bb;
      A[j]  = a*A[j];
    }
  }
  float* Ao = Aout + (size_t)g*NCH + c0;
  float* Bo = Bout + (size_t)g*NCH + c0;
  *(float4*)Ao     = make_float4(A[0],A[1],A[2],A[3]);
  *(float4*)(Ao+4) = make_float4(A[4],A[5],A[6],A[7]);
  *(float4*)Bo     = make_float4(Bc[0],Bc[1],Bc[2],Bc[3]);
  *(float4*)(Bo+4) = make_float4(Bc[4],Bc[5],Bc[6],Bc[7]);
}

// Pass 2: sequential scan over the 64 segment summaries per channel
__global__ __launch_bounds__(256) void scan_pass2(
    const float* __restrict__ A, const float* __restrict__ B,
    const float* __restrict__ h0, float* __restrict__ seg, float* __restrict__ hfin)
{
  int c = blockIdx.x*256 + threadIdx.x;   // 0..16383
  float s = h0[c];
  #pragma unroll 8
  for (int g=0; g<SEG; g++){
    seg[(size_t)g*NCH + c] = s;
    s = A[(size_t)g*NCH + c]*s + B[(size_t)g*NCH + c];
  }
  hfin[c] = s;
}

// Pass 3: replay each segment from its start state, fused output blend
__global__ __launch_bounds__(256) void scan_pass3(
    const ushort* __restrict__ z, const ushort* __restrict__ x, const ushort* __restrict__ hg,
    const float* __restrict__ prev, const float* __restrict__ seg,
    float* __restrict__ out)
{
  int t = blockIdx.x*256 + threadIdx.x;   // 0..131071
  int cg = t & (CG-1), g = t >> 11;
  int c0 = cg*8;
  float s[8];
  *(float4*)s     = *(const float4*)(seg + (size_t)g*NCH + c0);
  *(float4*)(s+4) = *(const float4*)(seg + (size_t)g*NCH + c0 + 4);
  size_t base = (size_t)g*SEGLEN*NCH + c0;
  #pragma unroll 2
  for (int i=0;i<SEGLEN;i++){
    size_t idx = base + (size_t)i*NCH;
    uint4 zv = *(const uint4*)(z+idx);
    uint4 xv = *(const uint4*)(x+idx);
    uint4 hv = *(const uint4*)(hg+idx);
    float4 p0 = *(const float4*)(prev+idx);
    float4 p1 = *(const float4*)(prev+idx+4);
    const ushort* zp=(const ushort*)&zv;
    const ushort* xp=(const ushort*)&xv;
    const ushort* hp=(const ushort*)&hv;
    float pv[8] = {p0.x,p0.y,p0.z,p0.w,p1.x,p1.y,p1.z,p1.w};
    float o[8];
    #pragma unroll
    for (int j=0;j<8;j++){
      float zf = bf2f(zp[j]);
      s[j] += zf*(bf2f(xp[j]) - s[j]);
      float hf = bf2f(hp[j]);
      o[j] = s[j] + hf*(pv[j] - s[j]);
    }
    *(float4*)(out+idx)   = make_float4(o[0],o[1],o[2],o[3]);
    *(float4*)(out+idx+4) = make_float4(o[4],o[5],o[6],o[7]);
  }
}

extern "C" void kernel_launch(void* const* d_in, const int* in_sizes, int n_in,
                              void* d_out, int out_size, void* d_ws, size_t ws_size,
                              hipStream_t stream) {
  const float* prev = (const float*)d_in[0];   // (L,B,D)
  const float* h0   = (const float*)d_in[1];   // (B,D)
  const float* W    = (const float*)d_in[2];   // (3D,D)
  const float* bias = (const float*)d_in[3];   // (3D,)
  float* out  = (float*)d_out;
  float* hfin = out + (size_t)M_DIM*D_DIM;

  char* ws = (char*)d_ws;
  ushort* Ab = (ushort*)ws;                                        // 64 MiB (dead after gemm)
  ushort* Wb = (ushort*)(ws + (size_t)M_DIM*K_DIM*2);              // 6 MiB
  ushort* xb = (ushort*)(ws + (size_t)M_DIM*K_DIM*2 + (size_t)N_DIM*K_DIM*2);
  ushort* zb = xb + (size_t)M_DIM*D_DIM;
  ushort* hb = zb + (size_t)M_DIM*D_DIM;
  // overlay scan scratch on Ab's region (only live after gemm completes)
  float* Abuf = (float*)ws;                     // SEG*NCH floats = 4 MiB
  float* Bbuf = Abuf + (size_t)SEG*NCH;         // 4 MiB
  float* segb = Bbuf + (size_t)SEG*NCH;         // 4 MiB

  cvt8<<<(M_DIM*K_DIM/8 + 255)/256, 256, 0, stream>>>(prev, Ab, M_DIM*K_DIM/8);
  cvt8<<<(N_DIM*K_DIM/8 + 255)/256, 256, 0, stream>>>(W,    Wb, N_DIM*K_DIM/8);
  gemm_sru<<<(M_DIM/256)*(N_DIM/256), 1024, 0, stream>>>(Ab, Wb, bias, xb, zb, hb);
  scan_pass1<<<(CG*SEG)/256, 256, 0, stream>>>(zb, xb, Abuf, Bbuf);
  scan_pass2<<<NCH/256, 256, 0, stream>>>(Abuf, Bbuf, h0, segb, hfin);
  scan_pass3<<<(CG*SEG)/256, 256, 0, stream>>>(zb, xb, hb, prev, segb, out);
}

// Round 11
// 407.384 us; speedup vs baseline: 1.2235x; 1.2235x over previous
//
#include <hip/hip_runtime.h>
#include <cstdint>

#define L_DIM 2048
#define B_DIM 16
#define D_DIM 1024
#define M_DIM (L_DIM*B_DIM)   // 32768
#define N_DIM (3*D_DIM)       // 3072
#define K_DIM D_DIM           // 1024
#define NCH   (B_DIM*D_DIM)   // 16384 channels
#define SEG   64
#define SEGLEN (L_DIM/SEG)    // 32
#define CG    (NCH/8)         // 2048 channel-groups of 8

#define BK 64                 // K per tile-step
#define NKT (K_DIM/BK)        // 16 K-tiles
#define BUF 65536             // bytes per LDS buffer: A 32KB (8 slabs x 4KB) + B 32KB
#define PANB 32768            // bytes per panel (256 rows x 64 K bf16, slab-major)

typedef __bf16 bf16x8 __attribute__((ext_vector_type(8)));
typedef float f32x16 __attribute__((ext_vector_type(16)));

__device__ inline float bf2f(ushort u){ return __uint_as_float(((unsigned)u)<<16); }
__device__ inline ushort f2bf(float f){
  unsigned u = __float_as_uint(f);
  u += 0x7fffu + ((u>>16)&1u);          // RTNE
  return (ushort)(u>>16);
}

// fp32 row-major (rows x 1024) -> bf16 slab-major panels.
// Panel (rb, kt) = rows [rb*256,rb*256+256) x K [kt*64, kt*64+64), stored as
// 8 slabs (16B of K) x 256 rows x 16B, contiguous 32KB. blockIdx = rb*16+kt.
__global__ __launch_bounds__(1024) void cvt_panel(const float* __restrict__ src,
                                                  char* __restrict__ dst){
  __shared__ char lds[PANB];
  const int t = threadIdx.x;
  const int rb = blockIdx.x >> 4, kt = blockIdx.x & 15;
  // read: thread t -> row t>>2, 16 floats at k = kt*64 + (t&3)*16 (coalesced)
  const float* s = src + (size_t)(rb*256 + (t>>2))*K_DIM + kt*64 + (t&3)*16;
  float4 f0 = *(const float4*)(s);
  float4 f1 = *(const float4*)(s+4);
  float4 f2 = *(const float4*)(s+8);
  float4 f3 = *(const float4*)(s+12);
  ushort h[16] = {f2bf(f0.x),f2bf(f0.y),f2bf(f0.z),f2bf(f0.w),
                  f2bf(f1.x),f2bf(f1.y),f2bf(f1.z),f2bf(f1.w),
                  f2bf(f2.x),f2bf(f2.y),f2bf(f2.z),f2bf(f2.w),
                  f2bf(f3.x),f2bf(f3.y),f2bf(f3.z),f2bf(f3.w)};
  // 16 bf16 = slabs s0,s0+1 (s0=(t&3)*2) of row t>>2 ; 2-way bank alias (free)
  const int row = t>>2, slb = (t&3)*2;
  *(uint4*)(lds + slb*4096     + row*16) = *(const uint4*)(h);
  *(uint4*)(lds + (slb+1)*4096 + row*16) = *(const uint4*)(h+8);
  __syncthreads();
  // write: linear panel image, both halves (conflict-free b128 reads, coalesced stores)
  char* pan = dst + (size_t)blockIdx.x*PANB;
  *(uint4*)(pan + t*16)         = *(const uint4*)(lds + t*16);
  *(uint4*)(pan + 16384 + t*16) = *(const uint4*)(lds + 16384 + t*16);
}

#define GLOAD(gp, lp) __builtin_amdgcn_global_load_lds( \
    (const __attribute__((address_space(1))) void*)(gp), \
    (__attribute__((address_space(3))) void*)(lp), 16, 0, 0)

// 256x256 tile, BK=64, 16 waves (4x4) of 64x64; mfma 32x32x16.
// A/B pre-tiled as slab-major panels -> staging is fully sequential and the
// LDS image is conflict-free without any swizzle.
__global__ __launch_bounds__(1024, 4) void gemm_sru(
    const char* __restrict__ gA,    // A panels: (mb*16+kt)*32KB
    const char* __restrict__ gB,    // B panels: (nb*16+kt)*32KB
    const float* __restrict__ bias, // N fp32
    ushort* __restrict__ xbuf, ushort* __restrict__ zbuf, ushort* __restrict__ hbuf)
{
  __shared__ ulong2 lds_[2*BUF/16];   // 128 KiB
  char* ldsb = (char*)lds_;

  const int tid  = threadIdx.x;
  const int lane = tid & 63, w = tid >> 6;
  const int wr = (w>>2)*64;            // wave row base (0..192)
  const int wc = (w&3)*64;             // wave col base (0..192)
  const int l31 = lane & 31, l5 = lane >> 5;

  // XCD L2-grouping swizzle: xcd x owns mb in [x*16, x*16+16), nb-major
  const int bid = blockIdx.x;
  const int xcd = bid & 7, idx = bid >> 3;        // idx 0..191
  const int mb = xcd*16 + idx/12, nb = idx % 12;
  const int bm = mb*256, bn = nb*256;

  const char* Apan = gA + (size_t)mb*16*PANB;
  const char* Bpan = gB + (size_t)nb*16*PANB;

  // per-lane frag read bases (slab-major): slab = ks*2 + l5, row = wr/wc + f*32 + l31
  const char* pA = ldsb + l5*4096 + (wr + l31)*16;
  const char* pB = ldsb + 32768 + l5*4096 + (wc + l31)*16;

  f32x16 acc[2][2];
  #pragma unroll
  for (int i=0;i<2;i++)
    #pragma unroll
    for (int j=0;j<2;j++)
      #pragma unroll
      for (int r=0;r<16;r++) acc[i][j][r] = 0.f;

#define STAGE(tt) do{ \
    char* d = ldsb + ((tt)&1)*BUF; \
    const char* ap = Apan + (size_t)(tt)*PANB; \
    const char* bp = Bpan + (size_t)(tt)*PANB; \
    GLOAD(ap + tid*16,         d + tid*16); \
    GLOAD(ap + 16384 + tid*16, d + 16384 + tid*16); \
    GLOAD(bp + tid*16,         d + 32768 + tid*16); \
    GLOAD(bp + 16384 + tid*16, d + 49152 + tid*16); \
  }while(0)

  // prologue: stage tile 0, wait, publish
  STAGE(0);
  __syncthreads();

  for (int t = 0; t < NKT; ++t) {
    const int bo = (t&1)*BUF;
    if (t < NKT-1) STAGE(t+1);      // other buffer; forced by tile-end syncthreads

    #pragma unroll
    for (int ks=0; ks<4; ++ks) {
      bf16x8 a0 = *(const bf16x8*)(pA + bo + ks*8192);
      bf16x8 a1 = *(const bf16x8*)(pA + bo + ks*8192 + 512);
      bf16x8 b0 = *(const bf16x8*)(pB + bo + ks*8192);
      bf16x8 b1 = *(const bf16x8*)(pB + bo + ks*8192 + 512);
      __builtin_amdgcn_s_setprio(1);
      acc[0][0] = __builtin_amdgcn_mfma_f32_32x32x16_bf16(a0, b0, acc[0][0], 0,0,0);
      acc[0][1] = __builtin_amdgcn_mfma_f32_32x32x16_bf16(a0, b1, acc[0][1], 0,0,0);
      acc[1][0] = __builtin_amdgcn_mfma_f32_32x32x16_bf16(a1, b0, acc[1][0], 0,0,0);
      acc[1][1] = __builtin_amdgcn_mfma_f32_32x32x16_bf16(a1, b1, acc[1][1], 0,0,0);
      __builtin_amdgcn_s_setprio(0);
    }
    __syncthreads();                // drains vmcnt (stage t+1 forced) + publishes
  }

  // ---- epilogue: acc -> LDS (bf16, bias+sigmoid, slot^row swizzle) -> coalesced ----
  // 32x32 C/D layout: col = lane&31, row = (reg&3) + 8*(reg>>2) + 4*(lane>>5)
  const int region = bn >> 10;
  ushort* dst = region==0 ? xbuf : (region==1 ? zbuf : hbuf);
  ushort* lds16 = (ushort*)ldsb;
  float bvv[2];
  bvv[0] = bias[bn + wc + l31];
  bvv[1] = bias[bn + wc + 32 + l31];

  #pragma unroll
  for (int fa=0; fa<2; ++fa)
    #pragma unroll
    for (int fb=0; fb<2; ++fb)
      #pragma unroll
      for (int r=0; r<16; ++r){
        int row = wr + fa*32 + (r&3) + ((r>>2)<<3) + (l5<<2);
        int col = wc + fb*32 + l31;
        float v = acc[fa][fb][r] + bvv[fb];
        if (region) v = 1.f/(1.f + __expf(-v));
        int slot = col >> 3;
        lds16[row*256 + (((slot ^ (row&31))&31)<<3) + (col&7)] = f2bf(v);
      }
  __syncthreads();
  const int cb = bn & (D_DIM-1);
  #pragma unroll
  for (int i=0;i<8;i++){
    int off = i*16384 + tid*16;               // byte in 256x512B tile
    int row = off >> 9;
    int slot = (off >> 4) & 31;
    int dcol = (off & 511) >> 1;
    const char* src = ldsb + row*512 + (((slot ^ (row&31))&31)<<4);
    *(uint4*)(dst + (size_t)(bm+row)*D_DIM + cb + dcol) = *(const uint4*)src;
  }
#undef STAGE
}

// Pass 1: per (segment, 8-channel group) compose affine coefficients
__global__ __launch_bounds__(256) void scan_pass1(
    const ushort* __restrict__ z, const ushort* __restrict__ x,
    float* __restrict__ Aout, float* __restrict__ Bout)
{
  int t = blockIdx.x*256 + threadIdx.x;   // 0..131071
  int cg = t & (CG-1), g = t >> 11;       // CG = 2048 = 2^11
  int c0 = cg*8;
  size_t base = (size_t)g*SEGLEN*NCH + c0;
  float A[8], Bc[8];
  #pragma unroll
  for (int j=0;j<8;j++){ A[j]=1.f; Bc[j]=0.f; }
  #pragma unroll 4
  for (int i=0;i<SEGLEN;i++){
    uint4 zv = *(const uint4*)(z + base + (size_t)i*NCH);
    uint4 xv = *(const uint4*)(x + base + (size_t)i*NCH);
    const ushort* zp = (const ushort*)&zv;
    const ushort* xp = (const ushort*)&xv;
    #pragma unroll
    for (int j=0;j<8;j++){
      float zf = bf2f(zp[j]);
      float a  = 1.f - zf;
      float bb = zf * bf2f(xp[j]);
      Bc[j] = a*Bc[j] + bb;
      A[j]  = a*A[j];
    }
  }
  float* Ao = Aout + (size_t)g*NCH + c0;
  float* Bo = Bout + (size_t)g*NCH + c0;
  *(float4*)Ao     = make_float4(A[0],A[1],A[2],A[3]);
  *(float4*)(Ao+4) = make_float4(A[4],A[5],A[6],A[7]);
  *(float4*)Bo     = make_float4(Bc[0],Bc[1],Bc[2],Bc[3]);
  *(float4*)(Bo+4) = make_float4(Bc[4],Bc[5],Bc[6],Bc[7]);
}

// Pass 2: sequential scan over the 64 segment summaries per channel
__global__ __launch_bounds__(256) void scan_pass2(
    const float* __restrict__ A, const float* __restrict__ B,
    const float* __restrict__ h0, float* __restrict__ seg, float* __restrict__ hfin)
{
  int c = blockIdx.x*256 + threadIdx.x;   // 0..16383
  float s = h0[c];
  #pragma unroll 8
  for (int g=0; g<SEG; g++){
    seg[(size_t)g*NCH + c] = s;
    s = A[(size_t)g*NCH + c]*s + B[(size_t)g*NCH + c];
  }
  hfin[c] = s;
}

// Pass 3: replay each segment from its start state, fused output blend
__global__ __launch_bounds__(256) void scan_pass3(
    const ushort* __restrict__ z, const ushort* __restrict__ x, const ushort* __restrict__ hg,
    const float* __restrict__ prev, const float* __restrict__ seg,
    float* __restrict__ out)
{
  int t = blockIdx.x*256 + threadIdx.x;   // 0..131071
  int cg = t & (CG-1), g = t >> 11;
  int c0 = cg*8;
  float s[8];
  *(float4*)s     = *(const float4*)(seg + (size_t)g*NCH + c0);
  *(float4*)(s+4) = *(const float4*)(seg + (size_t)g*NCH + c0 + 4);
  size_t base = (size_t)g*SEGLEN*NCH + c0;
  #pragma unroll 2
  for (int i=0;i<SEGLEN;i++){
    size_t idx = base + (size_t)i*NCH;
    uint4 zv = *(const uint4*)(z+idx);
    uint4 xv = *(const uint4*)(x+idx);
    uint4 hv = *(const uint4*)(hg+idx);
    float4 p0 = *(const float4*)(prev+idx);
    float4 p1 = *(const float4*)(prev+idx+4);
    const ushort* zp=(const ushort*)&zv;
    const ushort* xp=(const ushort*)&xv;
    const ushort* hp=(const ushort*)&hv;
    float pv[8] = {p0.x,p0.y,p0.z,p0.w,p1.x,p1.y,p1.z,p1.w};
    float o[8];
    #pragma unroll
    for (int j=0;j<8;j++){
      float zf = bf2f(zp[j]);
      s[j] += zf*(bf2f(xp[j]) - s[j]);
      float hf = bf2f(hp[j]);
      o[j] = s[j] + hf*(pv[j] - s[j]);
    }
    *(float4*)(out+idx)   = make_float4(o[0],o[1],o[2],o[3]);
    *(float4*)(out+idx+4) = make_float4(o[4],o[5],o[6],o[7]);
  }
}

extern "C" void kernel_launch(void* const* d_in, const int* in_sizes, int n_in,
                              void* d_out, int out_size, void* d_ws, size_t ws_size,
                              hipStream_t stream) {
  const float* prev = (const float*)d_in[0];   // (L,B,D)
  const float* h0   = (const float*)d_in[1];   // (B,D)
  const float* W    = (const float*)d_in[2];   // (3D,D)
  const float* bias = (const float*)d_in[3];   // (3D,)
  float* out  = (float*)d_out;
  float* hfin = out + (size_t)M_DIM*D_DIM;

  char* ws = (char*)d_ws;
  char* Ab = ws;                                                   // 64 MiB (panels; dead after gemm)
  char* Wb = ws + (size_t)M_DIM*K_DIM*2;                           // 6 MiB (panels)
  ushort* xb = (ushort*)(ws + (size_t)M_DIM*K_DIM*2 + (size_t)N_DIM*K_DIM*2);
  ushort* zb = xb + (size_t)M_DIM*D_DIM;
  ushort* hb = zb + (size_t)M_DIM*D_DIM;
  // overlay scan scratch on Ab's region (only live after gemm completes)
  float* Abuf = (float*)ws;                     // SEG*NCH floats = 4 MiB
  float* Bbuf = Abuf + (size_t)SEG*NCH;         // 4 MiB
  float* segb = Bbuf + (size_t)SEG*NCH;         // 4 MiB

  cvt_panel<<<(M_DIM/256)*16, 1024, 0, stream>>>(prev, Ab);
  cvt_panel<<<(N_DIM/256)*16, 1024, 0, stream>>>(W,    Wb);
  gemm_sru<<<(M_DIM/256)*(N_DIM/256), 1024, 0, stream>>>(Ab, Wb, bias, xb, zb, hb);
  scan_pass1<<<(CG*SEG)/256, 256, 0, stream>>>(zb, xb, Abuf, Bbuf);
  scan_pass2<<<NCH/256, 256, 0, stream>>>(Abuf, Bbuf, h0, segb, hfin);
  scan_pass3<<<(CG*SEG)/256, 256, 0, stream>>>(zb, xb, hb, prev, segb, out);
}

// Round 12
// 405.408 us; speedup vs baseline: 1.2295x; 1.0049x over previous
//
#include <hip/hip_runtime.h>
#include <cstdint>

#define L_DIM 2048
#define B_DIM 16
#define D_DIM 1024
#define M_DIM (L_DIM*B_DIM)   // 32768
#define N_DIM (3*D_DIM)       // 3072
#define K_DIM D_DIM           // 1024
#define NCH   (B_DIM*D_DIM)   // 16384 channels
#define SEG   64
#define SEGLEN (L_DIM/SEG)    // 32
#define CG    (NCH/8)         // 2048 channel-groups of 8

#define BK 64                 // K per tile-step
#define NKT (K_DIM/BK)        // 16 K-tiles
#define BUF 65536             // bytes per LDS buffer: A 32KB (8 slabs x 4KB) + B 32KB
#define PANB 32768            // bytes per panel (256 rows x 64 K bf16, slab-major)

typedef __bf16 bf16x8 __attribute__((ext_vector_type(8)));
typedef float f32x16 __attribute__((ext_vector_type(16)));

__device__ inline float bf2f(ushort u){ return __uint_as_float(((unsigned)u)<<16); }
__device__ inline ushort f2bf(float f){
  unsigned u = __float_as_uint(f);
  u += 0x7fffu + ((u>>16)&1u);          // RTNE
  return (ushort)(u>>16);
}

// fp32 row-major (rows x 1024) -> bf16 slab-major panels.
// Panel (rb, kt) = rows [rb*256,rb*256+256) x K [kt*64, kt*64+64), stored as
// 8 slabs (16B of K) x 256 rows x 16B, contiguous 32KB. blockIdx = rb*16+kt.
__global__ __launch_bounds__(1024) void cvt_panel(const float* __restrict__ src,
                                                  char* __restrict__ dst){
  __shared__ char lds[PANB];
  const int t = threadIdx.x;
  const int rb = blockIdx.x >> 4, kt = blockIdx.x & 15;
  const float* s = src + (size_t)(rb*256 + (t>>2))*K_DIM + kt*64 + (t&3)*16;
  float4 f0 = *(const float4*)(s);
  float4 f1 = *(const float4*)(s+4);
  float4 f2 = *(const float4*)(s+8);
  float4 f3 = *(const float4*)(s+12);
  ushort h[16] = {f2bf(f0.x),f2bf(f0.y),f2bf(f0.z),f2bf(f0.w),
                  f2bf(f1.x),f2bf(f1.y),f2bf(f1.z),f2bf(f1.w),
                  f2bf(f2.x),f2bf(f2.y),f2bf(f2.z),f2bf(f2.w),
                  f2bf(f3.x),f2bf(f3.y),f2bf(f3.z),f2bf(f3.w)};
  const int row = t>>2, slb = (t&3)*2;
  *(uint4*)(lds + slb*4096     + row*16) = *(const uint4*)(h);
  *(uint4*)(lds + (slb+1)*4096 + row*16) = *(const uint4*)(h+8);
  __syncthreads();
  char* pan = dst + (size_t)blockIdx.x*PANB;
  *(uint4*)(pan + t*16)         = *(const uint4*)(lds + t*16);
  *(uint4*)(pan + 16384 + t*16) = *(const uint4*)(lds + 16384 + t*16);
}

#define GLOAD(gp, lp) __builtin_amdgcn_global_load_lds( \
    (const __attribute__((address_space(1))) void*)(gp), \
    (__attribute__((address_space(3))) void*)(lp), 16, 0, 0)

// 256x256 tile, BK=64, 8 waves (2x4) of 128x64 each; mfma 32x32x16.
// Register blocking 4x2 -> 6 LDS reads feed 8 MFMAs (ratio 0.75, was 1.0).
__global__ __launch_bounds__(512, 2) void gemm_sru(
    const char* __restrict__ gA,    // A panels: (mb*16+kt)*32KB
    const char* __restrict__ gB,    // B panels: (nb*16+kt)*32KB
    const float* __restrict__ bias, // N fp32
    ushort* __restrict__ xbuf, ushort* __restrict__ zbuf, ushort* __restrict__ hbuf)
{
  __shared__ ulong2 lds_[2*BUF/16];   // 128 KiB
  char* ldsb = (char*)lds_;

  const int tid  = threadIdx.x;
  const int lane = tid & 63, w = tid >> 6;
  const int wr = (w>>2)*128;           // wave row base (0 or 128)
  const int wc = (w&3)*64;             // wave col base (0..192)
  const int l31 = lane & 31, l5 = lane >> 5;

  // XCD L2-grouping swizzle: xcd x owns mb in [x*16, x*16+16), nb-major
  const int bid = blockIdx.x;
  const int xcd = bid & 7, idx = bid >> 3;        // idx 0..191
  const int mb = xcd*16 + idx/12, nb = idx % 12;
  const int bm = mb*256, bn = nb*256;

  const char* Apan = gA + (size_t)mb*16*PANB;
  const char* Bpan = gB + (size_t)nb*16*PANB;

  // per-lane frag read bases (slab-major): slab = ks*2 + l5, row/col + l31
  const char* pA = ldsb + l5*4096 + (wr + l31)*16;
  const char* pB = ldsb + 32768 + l5*4096 + (wc + l31)*16;

  f32x16 acc[4][2];
  #pragma unroll
  for (int i=0;i<4;i++)
    #pragma unroll
    for (int j=0;j<2;j++)
      #pragma unroll
      for (int r=0;r<16;r++) acc[i][j][r] = 0.f;

#define STAGE(tt) do{ \
    char* d = ldsb + ((tt)&1)*BUF; \
    const char* ap = Apan + (size_t)(tt)*PANB; \
    const char* bp = Bpan + (size_t)(tt)*PANB; \
    GLOAD(ap + tid*16,         d + tid*16); \
    GLOAD(ap + 8192  + tid*16, d + 8192  + tid*16); \
    GLOAD(ap + 16384 + tid*16, d + 16384 + tid*16); \
    GLOAD(ap + 24576 + tid*16, d + 24576 + tid*16); \
    GLOAD(bp + tid*16,         d + 32768 + tid*16); \
    GLOAD(bp + 8192  + tid*16, d + 40960 + tid*16); \
    GLOAD(bp + 16384 + tid*16, d + 49152 + tid*16); \
    GLOAD(bp + 24576 + tid*16, d + 57344 + tid*16); \
  }while(0)

  // prologue: stage tile 0, wait, publish
  STAGE(0);
  __syncthreads();

  for (int t = 0; t < NKT; ++t) {
    const int bo = (t&1)*BUF;
    if (t < NKT-1) STAGE(t+1);      // other buffer; forced by tile-end syncthreads

    #pragma unroll
    for (int ks=0; ks<4; ++ks) {
      bf16x8 a0 = *(const bf16x8*)(pA + bo + ks*8192);
      bf16x8 a1 = *(const bf16x8*)(pA + bo + ks*8192 + 512);
      bf16x8 a2 = *(const bf16x8*)(pA + bo + ks*8192 + 1024);
      bf16x8 a3 = *(const bf16x8*)(pA + bo + ks*8192 + 1536);
      bf16x8 b0 = *(const bf16x8*)(pB + bo + ks*8192);
      bf16x8 b1 = *(const bf16x8*)(pB + bo + ks*8192 + 512);
      __builtin_amdgcn_s_setprio(1);
      acc[0][0] = __builtin_amdgcn_mfma_f32_32x32x16_bf16(a0, b0, acc[0][0], 0,0,0);
      acc[0][1] = __builtin_amdgcn_mfma_f32_32x32x16_bf16(a0, b1, acc[0][1], 0,0,0);
      acc[1][0] = __builtin_amdgcn_mfma_f32_32x32x16_bf16(a1, b0, acc[1][0], 0,0,0);
      acc[1][1] = __builtin_amdgcn_mfma_f32_32x32x16_bf16(a1, b1, acc[1][1], 0,0,0);
      acc[2][0] = __builtin_amdgcn_mfma_f32_32x32x16_bf16(a2, b0, acc[2][0], 0,0,0);
      acc[2][1] = __builtin_amdgcn_mfma_f32_32x32x16_bf16(a2, b1, acc[2][1], 0,0,0);
      acc[3][0] = __builtin_amdgcn_mfma_f32_32x32x16_bf16(a3, b0, acc[3][0], 0,0,0);
      acc[3][1] = __builtin_amdgcn_mfma_f32_32x32x16_bf16(a3, b1, acc[3][1], 0,0,0);
      __builtin_amdgcn_s_setprio(0);
    }
    __syncthreads();                // drains vmcnt (stage t+1 forced) + publishes
  }

  // ---- epilogue: acc -> LDS (bf16, bias+sigmoid, slot^row swizzle) -> coalesced ----
  // 32x32 C/D layout: col = lane&31, row = (reg&3) + 8*(reg>>2) + 4*(lane>>5)
  const int region = bn >> 10;
  ushort* dst = region==0 ? xbuf : (region==1 ? zbuf : hbuf);
  ushort* lds16 = (ushort*)ldsb;
  float bvv[2];
  bvv[0] = bias[bn + wc + l31];
  bvv[1] = bias[bn + wc + 32 + l31];

  #pragma unroll
  for (int fa=0; fa<4; ++fa)
    #pragma unroll
    for (int fb=0; fb<2; ++fb)
      #pragma unroll
      for (int r=0; r<16; ++r){
        int row = wr + fa*32 + (r&3) + ((r>>2)<<3) + (l5<<2);
        int col = wc + fb*32 + l31;
        float v = acc[fa][fb][r] + bvv[fb];
        if (region) v = 1.f/(1.f + __expf(-v));
        int slot = col >> 3;
        lds16[row*256 + (((slot ^ (row&31))&31)<<3) + (col&7)] = f2bf(v);
      }
  __syncthreads();
  const int cb = bn & (D_DIM-1);
  #pragma unroll
  for (int i=0;i<16;i++){
    int off = i*8192 + tid*16;               // byte in 256x512B tile
    int row = off >> 9;
    int slot = (off >> 4) & 31;
    int dcol = (off & 511) >> 1;
    const char* src = ldsb + row*512 + (((slot ^ (row&31))&31)<<4);
    *(uint4*)(dst + (size_t)(bm+row)*D_DIM + cb + dcol) = *(const uint4*)src;
  }
#undef STAGE
}

// Pass 1: per (segment, 8-channel group) compose affine coefficients
__global__ __launch_bounds__(256) void scan_pass1(
    const ushort* __restrict__ z, const ushort* __restrict__ x,
    float* __restrict__ Aout, float* __restrict__ Bout)
{
  int t = blockIdx.x*256 + threadIdx.x;   // 0..131071
  int cg = t & (CG-1), g = t >> 11;       // CG = 2048 = 2^11
  int c0 = cg*8;
  size_t base = (size_t)g*SEGLEN*NCH + c0;
  float A[8], Bc[8];
  #pragma unroll
  for (int j=0;j<8;j++){ A[j]=1.f; Bc[j]=0.f; }
  #pragma unroll 4
  for (int i=0;i<SEGLEN;i++){
    uint4 zv = *(const uint4*)(z + base + (size_t)i*NCH);
    uint4 xv = *(const uint4*)(x + base + (size_t)i*NCH);
    const ushort* zp = (const ushort*)&zv;
    const ushort* xp = (const ushort*)&xv;
    #pragma unroll
    for (int j=0;j<8;j++){
      float zf = bf2f(zp[j]);
      float a  = 1.f - zf;
      float bb = zf * bf2f(xp[j]);
      Bc[j] = a*Bc[j] + bb;
      A[j]  = a*A[j];
    }
  }
  float* Ao = Aout + (size_t)g*NCH + c0;
  float* Bo = Bout + (size_t)g*NCH + c0;
  *(float4*)Ao     = make_float4(A[0],A[1],A[2],A[3]);
  *(float4*)(Ao+4) = make_float4(A[4],A[5],A[6],A[7]);
  *(float4*)Bo     = make_float4(Bc[0],Bc[1],Bc[2],Bc[3]);
  *(float4*)(Bo+4) = make_float4(Bc[4],Bc[5],Bc[6],Bc[7]);
}

// Pass 2: sequential scan over the 64 segment summaries per channel
__global__ __launch_bounds__(256) void scan_pass2(
    const float* __restrict__ A, const float* __restrict__ B,
    const float* __restrict__ h0, float* __restrict__ seg, float* __restrict__ hfin)
{
  int c = blockIdx.x*256 + threadIdx.x;   // 0..16383
  float s = h0[c];
  #pragma unroll 8
  for (int g=0; g<SEG; g++){
    seg[(size_t)g*NCH + c] = s;
    s = A[(size_t)g*NCH + c]*s + B[(size_t)g*NCH + c];
  }
  hfin[c] = s;
}

// Pass 3: replay each segment from its start state, fused output blend
__global__ __launch_bounds__(256) void scan_pass3(
    const ushort* __restrict__ z, const ushort* __restrict__ x, const ushort* __restrict__ hg,
    const float* __restrict__ prev, const float* __restrict__ seg,
    float* __restrict__ out)
{
  int t = blockIdx.x*256 + threadIdx.x;   // 0..131071
  int cg = t & (CG-1), g = t >> 11;
  int c0 = cg*8;
  float s[8];
  *(float4*)s     = *(const float4*)(seg + (size_t)g*NCH + c0);
  *(float4*)(s+4) = *(const float4*)(seg + (size_t)g*NCH + c0 + 4);
  size_t base = (size_t)g*SEGLEN*NCH + c0;
  #pragma unroll 2
  for (int i=0;i<SEGLEN;i++){
    size_t idx = base + (size_t)i*NCH;
    uint4 zv = *(const uint4*)(z+idx);
    uint4 xv = *(const uint4*)(x+idx);
    uint4 hv = *(const uint4*)(hg+idx);
    float4 p0 = *(const float4*)(prev+idx);
    float4 p1 = *(const float4*)(prev+idx+4);
    const ushort* zp=(const ushort*)&zv;
    const ushort* xp=(const ushort*)&xv;
    const ushort* hp=(const ushort*)&hv;
    float pv[8] = {p0.x,p0.y,p0.z,p0.w,p1.x,p1.y,p1.z,p1.w};
    float o[8];
    #pragma unroll
    for (int j=0;j<8;j++){
      float zf = bf2f(zp[j]);
      s[j] += zf*(bf2f(xp[j]) - s[j]);
      float hf = bf2f(hp[j]);
      o[j] = s[j] + hf*(pv[j] - s[j]);
    }
    *(float4*)(out+idx)   = make_float4(o[0],o[1],o[2],o[3]);
    *(float4*)(out+idx+4) = make_float4(o[4],o[5],o[6],o[7]);
  }
}

extern "C" void kernel_launch(void* const* d_in, const int* in_sizes, int n_in,
                              void* d_out, int out_size, void* d_ws, size_t ws_size,
                              hipStream_t stream) {
  const float* prev = (const float*)d_in[0];   // (L,B,D)
  const float* h0   = (const float*)d_in[1];   // (B,D)
  const float* W    = (const float*)d_in[2];   // (3D,D)
  const float* bias = (const float*)d_in[3];   // (3D,)
  float* out  = (float*)d_out;
  float* hfin = out + (size_t)M_DIM*D_DIM;

  char* ws = (char*)d_ws;
  char* Ab = ws;                                                   // 64 MiB (panels; dead after gemm)
  char* Wb = ws + (size_t)M_DIM*K_DIM*2;                           // 6 MiB (panels)
  ushort* xb = (ushort*)(ws + (size_t)M_DIM*K_DIM*2 + (size_t)N_DIM*K_DIM*2);
  ushort* zb = xb + (size_t)M_DIM*D_DIM;
  ushort* hb = zb + (size_t)M_DIM*D_DIM;
  // overlay scan scratch on Ab's region (only live after gemm completes)
  float* Abuf = (float*)ws;                     // SEG*NCH floats = 4 MiB
  float* Bbuf = Abuf + (size_t)SEG*NCH;         // 4 MiB
  float* segb = Bbuf + (size_t)SEG*NCH;         // 4 MiB

  cvt_panel<<<(M_DIM/256)*16, 1024, 0, stream>>>(prev, Ab);
  cvt_panel<<<(N_DIM/256)*16, 1024, 0, stream>>>(W,    Wb);
  gemm_sru<<<(M_DIM/256)*(N_DIM/256), 512, 0, stream>>>(Ab, Wb, bias, xb, zb, hb);
  scan_pass1<<<(CG*SEG)/256, 256, 0, stream>>>(zb, xb, Abuf, Bbuf);
  scan_pass2<<<NCH/256, 256, 0, stream>>>(Abuf, Bbuf, h0, segb, hfin);
  scan_pass3<<<(CG*SEG)/256, 256, 0, stream>>>(zb, xb, hb, prev, segb, out);
}